// Round 3
// baseline (86.534 us; speedup 1.0000x reference)
//
#include <hip/hip_runtime.h>

// AverageSpanExtractor: out[b,n,:] = mask[b,n] * mean(seq[b, start:end, :])
// B=8, S=2048, D=512, N=1024, width in [1,20].
//
// One 128-thread block per span; thread t owns float4 #t of the D=512 row.
// Round 3 changes vs round 2:
//  - Width is block-uniform -> predicated group-of-5 unroll (max 4 groups,
//    wave-uniform branches, 5 loads in flight per wait, no scalar tail).
//    Invalid rows clamp to row 0 (L1-hit) with weight 0.
//  - Non-temporal output store: 16 MB output stream no longer evicts the
//    per-XCD 4 MB seq slice from L2.
//  - int2 span-metadata load.

#define DV4   128   // D / 4
#define BATCH 8
#define NSPAN 1024
#define SEQ_S 2048

typedef float f4v __attribute__((ext_vector_type(4)));

__global__ __launch_bounds__(128) void span_avg_kernel(
    const f4v*  __restrict__ seq,   // [B, S, D/4]
    const int2* __restrict__ spans, // [B, N] (start, exclusive end)
    const int*  __restrict__ msk,   // [B, N]
    f4v*        __restrict__ out)   // [B, N, D/4]
{
    const int blk = blockIdx.x;       // 0..8191
    const int b = blk & (BATCH - 1);  // XCD-affine: b == XCD id (round-robin)
    const int n = blk >> 3;
    const int sid = b * NSPAN + n;

    const int2 se = spans[sid];
    const int start = se.x;
    const int width = se.y - se.x;    // 1..20 guaranteed, block-uniform

    const int t = threadIdx.x;        // 0..127
    const f4v* row = seq + ((size_t)b * SEQ_S + (size_t)start) * DV4 + t;

    f4v acc = (f4v)(0.f);

    #pragma unroll
    for (int g = 0; g < 4; ++g) {
        if (g * 5 < width) {          // wave-uniform (width uniform per block)
            f4v   v[5];
            float wt[5];
            #pragma unroll
            for (int k = 0; k < 5; ++k) {
                const int j = g * 5 + k;
                const int r = (j < width) ? j : 0;   // clamp -> L1 hit
                wt[k] = (j < width) ? 1.f : 0.f;
                v[k] = row[(size_t)r * DV4];
            }
            #pragma unroll
            for (int k = 0; k < 5; ++k) {
                acc += v[k] * wt[k];
            }
        }
    }

    const float scale = (float)msk[sid] / (float)width;
    acc *= scale;

    __builtin_nontemporal_store(acc, &out[(size_t)sid * DV4 + t]);
}

extern "C" void kernel_launch(void* const* d_in, const int* in_sizes, int n_in,
                              void* d_out, int out_size, void* d_ws, size_t ws_size,
                              hipStream_t stream) {
    const float* seq  = (const float*)d_in[0];   // [B,S,D] fp32
    const int*   sp   = (const int*)d_in[1];     // [B,N,2] int
    const int*   mask = (const int*)d_in[2];     // [B,N] int
    float*       out  = (float*)d_out;           // [B,N,D] fp32

    dim3 grid(BATCH * NSPAN);
    dim3 block(128);
    span_avg_kernel<<<grid, block, 0, stream>>>(
        (const f4v*)seq, (const int2*)sp, mask, (f4v*)out);
}